// Round 5
// baseline (245.689 us; speedup 1.0000x reference)
//
#include <hip/hip_runtime.h>

// ---------------------------------------------------------------------------
// RoPE attention: out = softmax(mask(RoPE(xWq^T) @ RoPE(xWk^T)^T / sqrt(d))) @ (xWv^T)
// B=4, T=2048, d=1024. fp32 in/out, bf16 MFMA internally.
// R16 -> R17: ATTRIBUTION round. Evidence: (a) R16's qkv is byte-identical to
// R14's yet measured 89 vs 63 us, with ALL hbm_gbps figures down ~40% in
// rounds 3-4 vs 0-2 => container-speed variance; only within-round structure
// is trustworthy. (b) Five rounds of top-5 show ONLY qkv => s/pv durations
// have never been observed. Changes:
//  (1) split qkv into qk_rope_gemm (N=2048, grid 64x16) + v_gemm (N=1024,
//      grid 64x8): same gemm_body, same accumulation order (absmax must stay
//      0.01171875); biggest dispatch drops to ~2/3 => s_gemm/pv_gemm MUST
//      enter the top-5 next round with real MfmaUtil/occupancy.
//  (2) fallback launcher path deleted (R12-R14 always used Wb at ws+64MB =>
//      ws >= 70.06 MB guaranteed); dispatch sequence now unambiguous:
//      cvt, qk, v, s, pv(z23), pv(z01). v runs before s so S01's xb overlay
//      is safe (stream-ordered).
// Pre-committed reads: s>50us -> s epilogue/occupancy next; pv pair >55us ->
// pv intensity; all near-ideal but total >=215 normalized -> inter-kernel
// slop -> persistent/cooperative. Predicted: total neutral +-3%.
// ---------------------------------------------------------------------------

typedef float f32x4 __attribute__((ext_vector_type(4)));
typedef __bf16 bf16x8 __attribute__((ext_vector_type(8)));

#define BM 128
#define BN 128
#define BK 64  // ushorts per LDS tile row; 128x64x2B = 16 KB per buffer

__device__ __forceinline__ unsigned short f2bf(float f) {
  union { float f; unsigned int u; } c; c.f = f;
  unsigned int u = c.u;
  u += 0x7fffu + ((u >> 16) & 1u);  // round-nearest-even
  return (unsigned short)(u >> 16);
}
__device__ __forceinline__ float bf2f(unsigned short h) {
  union { unsigned int u; float f; } c; c.u = ((unsigned int)h) << 16;
  return c.f;
}

__device__ __forceinline__ void async16(const unsigned short* gp, unsigned short* lp) {
  __builtin_amdgcn_global_load_lds(
      (const __attribute__((address_space(1))) void*)gp,
      (__attribute__((address_space(3))) void*)lp, 16, 0, 0);
}

// ---------------------------------------------------------------------------
// All fp32->bf16 casts in one kernel; last block zeroes rowsums.
__global__ __launch_bounds__(256) void cvt_all(
    const float4* __restrict__ x, const float4* __restrict__ wq,
    const float4* __restrict__ wk, const float4* __restrict__ wv,
    ushort4* __restrict__ xb, ushort4* __restrict__ wb,
    float4* __restrict__ rowsums) {
  int b = blockIdx.x, t = threadIdx.x;
  if (b == 11264) {  // zero rowsums: 4*2048 fp32 = 2048 float4
#pragma unroll
    for (int i = 0; i < 8; ++i) rowsums[i * 256 + t] = float4{0.f, 0.f, 0.f, 0.f};
    return;
  }
  const float4* src;
  ushort4* dst;
  long i;
  if (b < 8192) { src = x; dst = xb; i = (long)b * 256 + t; }
  else if (b < 9216) { src = wq; dst = wb; i = (long)(b - 8192) * 256 + t; }
  else if (b < 10240) { src = wk; dst = wb + 262144; i = (long)(b - 9216) * 256 + t; }
  else { src = wv; dst = wb + 524288; i = (long)(b - 10240) * 256 + t; }
  float4 v = src[i];
  ushort4 o;
  o.x = f2bf(v.x); o.y = f2bf(v.y); o.z = f2bf(v.z); o.w = f2bf(v.w);
  dst[i] = o;
}

// ---------------------------------------------------------------------------
// NT-GEMM K-loop, BK=64, single-buffer global_load_lds staging.
// C[m,n] = sum_k A[m,k]*B[n,k]. A-tile = IM*32 rows, B-tile = JN*32 rows,
// 4 waves (2x2); each wave IM*16 x JN*16 via 16x16x32 frags, two k-steps of
// 32 per LDS tile. LDS position f=p*256+tid (16-B units) holds row
// f>>3 = p*32+srow; staged chunk c = (tid&7)^(srow&7) is p-invariant
// ((p*32)%8==0) -> base pointers + uniform per-iter adds. XOR swizzle keeps
// the DMA's lane-contiguous LDS layout conflict-free for frag reads.
template <int IM, int JN>
__device__ __forceinline__ void gemm_body(
    const unsigned short* __restrict__ A, const unsigned short* __restrict__ B,
    unsigned short* As, unsigned short* Bs,
    int lda, int ldb, int m0, int n0, int ktiles,
    int tid, int lane, int wave, f32x4 (&acc)[IM][JN]) {
  const int wm = (wave >> 1) * (IM * 16);
  const int wn = (wave & 1) * (JN * 16);
  const int fm = lane & 15;
  const int q = lane >> 4;
  const int srow = tid >> 3;                 // 0..31
  const int c = (tid & 7) ^ (srow & 7);      // staged 16-B chunk (p-invariant)
  const unsigned short* Ab = A + (long)(m0 + srow) * lda + c * 8;
  const unsigned short* Bb = B + (long)(n0 + srow) * ldb + c * 8;
  unsigned short* ldA = As + tid * 8;
  unsigned short* ldB = Bs + tid * 8;

  for (int kt = 0; kt < ktiles; ++kt) {
    const long k0 = (long)kt * BK;
    __syncthreads();  // prior frag reads done before LDS overwrite
#pragma unroll
    for (int p = 0; p < IM; ++p)
      async16(Ab + (long)(p * 32) * lda + k0, ldA + p * 2048);
#pragma unroll
    for (int p = 0; p < JN; ++p)
      async16(Bb + (long)(p * 32) * ldb + k0, ldB + p * 2048);
    __syncthreads();  // compiler drains vmcnt(0): tiles ready

#pragma unroll
    for (int s = 0; s < 2; ++s) {  // two k-steps of 32
      bf16x8 af[IM], bfr[JN];
#pragma unroll
      for (int i = 0; i < IM; ++i) {
        int row = wm + i * 16 + fm;
        af[i] = *(const bf16x8*)&As[row * 64 + ((((s << 2) | q) ^ (row & 7)) << 3)];
      }
#pragma unroll
      for (int j = 0; j < JN; ++j) {
        int row = wn + j * 16 + fm;
        bfr[j] = *(const bf16x8*)&Bs[row * 64 + ((((s << 2) | q) ^ (row & 7)) << 3)];
      }
#pragma unroll
      for (int i = 0; i < IM; ++i)
#pragma unroll
        for (int j = 0; j < JN; ++j)
          acc[i][j] = __builtin_amdgcn_mfma_f32_16x16x32_bf16(af[i], bfr[j], acc[i][j], 0, 0, 0);
    }
  }
}

// ---------------------------------------------------------------------------
// Q/K projection + RoPE. A=xb[8192x1024], B=Wb[2048x1024]. Grid (bm=64, bn=16).
__global__ __launch_bounds__(256, 3) void qk_rope_gemm(
    const unsigned short* __restrict__ A, const unsigned short* __restrict__ B,
    unsigned short* __restrict__ Qr, unsigned short* __restrict__ Kr) {
  __shared__ __align__(16) unsigned short As[BM * BK];
  __shared__ __align__(16) unsigned short Bs[BN * BK];
  const int tid = threadIdx.x, lane = tid & 63, wave = tid >> 6;
  const int bm = blockIdx.x, bn = blockIdx.y;
  const int m0 = bm * BM, n0 = bn * BN;
  const int wm = (wave >> 1) * 64, wn = (wave & 1) * 64;
  const int q = lane >> 4, fm = lane & 15;

  f32x4 acc[4][4];
#pragma unroll
  for (int i = 0; i < 4; ++i)
#pragma unroll
    for (int j = 0; j < 4; ++j) acc[i][j] = (f32x4)(0.f);

  gemm_body<4, 4>(A, B, As, Bs, 1024, 1024, m0, n0, 16, tid, lane, wave, acc);

  // RoPE epilogue: pair (2c,2c+1) in adjacent lanes; chained angle addition.
  const float NEG = -13.287712379549449f / 1024.f;  // -log2(1e4)/1024
  unsigned short* dst = (n0 < 1024) ? Qr : Kr;
  const int t00 = (m0 + wm + q * 4) & 2047;
#pragma unroll
  for (int j = 0; j < 4; ++j) {
    int c = (n0 & 1023) + wn + j * 16 + fm;
    float th = exp2f((float)(c & ~1) * NEG);
    float sgn = (c & 1) ? 1.f : -1.f;
    float ang0 = (float)t00 * th;
    float cb = __cosf(ang0), sb = __sinf(ang0);
    float c1 = __cosf(th), s1 = __sinf(th);
    float c16 = __cosf(16.f * th), s16 = __sinf(16.f * th);
#pragma unroll
    for (int i = 0; i < 4; ++i) {
      int gmB = m0 + wm + i * 16 + q * 4;
      float cr = cb, sr = sb;
#pragma unroll
      for (int r = 0; r < 4; ++r) {
        float v = acc[i][j][r];
        float p = __shfl_xor(v, 1);
        dst[(long)(gmB + r) * 1024 + c] = f2bf(v * cr + sgn * p * sr);
        float crn = cr * c1 - sr * s1;
        sr = sr * c1 + cr * s1;
        cr = crn;
      }
      float cbn = cb * c16 - sb * s16;
      sb = sb * c16 + cb * s16;
      cb = cbn;
    }
  }
}

// ---------------------------------------------------------------------------
// V projection + transpose. A=xb[8192x1024], B=WbV[1024x1024]. Grid (64, 8).
__global__ __launch_bounds__(256, 3) void v_gemm(
    const unsigned short* __restrict__ A, const unsigned short* __restrict__ B,
    unsigned short* __restrict__ Vt) {
  __shared__ __align__(16) unsigned short As[BM * BK];
  __shared__ __align__(16) unsigned short Bs[BN * BK];
  const int tid = threadIdx.x, lane = tid & 63, wave = tid >> 6;
  const int bm = blockIdx.x, bn = blockIdx.y;
  const int m0 = bm * BM, n0 = bn * BN;
  const int wm = (wave >> 1) * 64, wn = (wave & 1) * 64;
  const int q = lane >> 4, fm = lane & 15;

  f32x4 acc[4][4];
#pragma unroll
  for (int i = 0; i < 4; ++i)
#pragma unroll
    for (int j = 0; j < 4; ++j) acc[i][j] = (f32x4)(0.f);

  gemm_body<4, 4>(A, B, As, Bs, 1024, 1024, m0, n0, 16, tid, lane, wave, acc);

  // Transpose to Vt[b][c][t]; 4 consecutive t per lane -> 8-B stores.
#pragma unroll
  for (int j = 0; j < 4; ++j) {
    int c = n0 + wn + j * 16 + fm;
#pragma unroll
    for (int i = 0; i < 4; ++i) {
      int gmB = m0 + wm + i * 16 + q * 4;
      int b = gmB >> 11, t = gmB & 2047;
      ushort4 pk;
      pk.x = f2bf(acc[i][j][0]);
      pk.y = f2bf(acc[i][j][1]);
      pk.z = f2bf(acc[i][j][2]);
      pk.w = f2bf(acc[i][j][3]);
      *(ushort4*)&Vt[((long)b * 1024 + c) * 2048 + t] = pk;
    }
  }
}

// ---------------------------------------------------------------------------
// E = exp(mask(Qr@Kr^T)/32) per batch (z), bf16, + rowsums. Compact triangular
// grid: 151 blocks/batch, decode (bm,bn) from linear idx (no no-op blocks).
// S routed per z: z<2 -> S01 (xb overlay), z>=2 -> S23 (d_out region).
__global__ __launch_bounds__(256, 3) void s_gemm(
    const unsigned short* __restrict__ Qr, const unsigned short* __restrict__ Kr,
    unsigned short* __restrict__ S01, unsigned short* __restrict__ S23,
    float* __restrict__ rowsums) {
  __shared__ __align__(16) unsigned short As[BM * BK];
  __shared__ __align__(16) unsigned short Bs[BN * BK];
  const int tid = threadIdx.x, lane = tid & 63, wave = tid >> 6;
  const int z = blockIdx.z;
  int idx = blockIdx.x, bm = 0;
#pragma unroll 1
  for (; bm < 16; ++bm) {  // counts per bm: min(bm+2,16); total 151
    int cnt = (bm + 2 > 16) ? 16 : bm + 2;
    if (idx < cnt) break;
    idx -= cnt;
  }
  const int bn = idx;
  const unsigned short* A = Qr + (long)z * 2048 * 1024;
  const unsigned short* B = Kr + (long)z * 2048 * 1024;
  unsigned short* S = (z < 2) ? (S01 + (long)z * 2048 * 2048)
                              : (S23 + (long)(z - 2) * 2048 * 2048);
  float* rs = rowsums + (long)z * 2048;
  const int m0 = bm * BM, n0 = bn * BN;
  const int wm = (wave >> 1) * 64, wn = (wave & 1) * 64;
  const int q = lane >> 4, fm = lane & 15;

  f32x4 acc[4][4];
#pragma unroll
  for (int i = 0; i < 4; ++i)
#pragma unroll
    for (int j = 0; j < 4; ++j) acc[i][j] = (f32x4)(0.f);

  gemm_body<4, 4>(A, B, As, Bs, 1024, 1024, m0, n0, 16, tid, lane, wave, acc);

  // rowsum scratch overlays Bs (frag reads complete after the final barrier)
  float* rsum = (float*)Bs;
  __syncthreads();
  if (tid < 128) rsum[tid] = 0.f;
  __syncthreads();

#pragma unroll
  for (int i = 0; i < 4; ++i) {
    int gmB = m0 + wm + i * 16 + q * 4;
    float ps[4] = {0.f, 0.f, 0.f, 0.f};
#pragma unroll
    for (int j = 0; j < 4; ++j) {
      int gn = n0 + wn + j * 16 + fm;
#pragma unroll
      for (int r = 0; r < 4; ++r) {
        float e = (gn <= gmB + r + 1) ? __expf(acc[i][j][r] * 0.03125f) : 0.f;
        unsigned short h = f2bf(e);
        S[(long)(gmB + r) * 2048 + gn] = h;
        ps[r] += bf2f(h);  // sum the rounded value (matches stored E)
      }
    }
#pragma unroll
    for (int r = 0; r < 4; ++r) {
      float v = ps[r];
      v += __shfl_xor(v, 1);
      v += __shfl_xor(v, 2);
      v += __shfl_xor(v, 4);
      v += __shfl_xor(v, 8);
      if (fm == 0) atomicAdd(&rsum[wm + i * 16 + q * 4 + r], v);
    }
  }
  __syncthreads();
  if (tid < 128) atomicAdd(&rs[m0 + tid], rsum[tid]);
}

// ---------------------------------------------------------------------------
// out = (E @ Vt^T) / rowsum, K-loop truncated causally. Tile 64x128 (IM=2).
// Grid dim3(8*NZ, 32): bn = x&7, zl = x>>3 (z = zoff+zl), bm = 31-y =>
// global long-first dispatch (all 32-ktile diagonal blocks first).
__global__ __launch_bounds__(256, 3) void pv_gemm(
    const unsigned short* __restrict__ S_base, const unsigned short* __restrict__ Vt,
    const float* __restrict__ rowsums, float* __restrict__ out, int zoff) {
  __shared__ __align__(16) unsigned short As[64 * BK];
  __shared__ __align__(16) unsigned short Bs[128 * BK];
  const int tid = threadIdx.x, lane = tid & 63, wave = tid >> 6;
  const int bn = blockIdx.x & 7;
  const int zl = blockIdx.x >> 3;
  const int z = zoff + zl;
  const int bm = 31 - blockIdx.y;  // 64-row granularity, longest-K first
  const unsigned short* A = S_base + (long)zl * 2048 * 2048;
  const unsigned short* B = Vt + (long)z * 1024 * 2048;
  const float* rs = rowsums + (long)z * 2048;
  float* C = out + (long)z * 2048 * 1024;
  int ktiles = bm + 2;  // keys valid up to q+1, q <= m0+63; BK=64
  if (ktiles > 32) ktiles = 32;
  const int m0 = bm * 64, n0 = bn * 128;
  const int wm = (wave >> 1) * 32, wn = (wave & 1) * 64;
  const int q = lane >> 4, fm = lane & 15;

  f32x4 acc[2][4];
#pragma unroll
  for (int i = 0; i < 2; ++i)
#pragma unroll
    for (int j = 0; j < 4; ++j) acc[i][j] = (f32x4)(0.f);

  gemm_body<2, 4>(A, B, As, Bs, 2048, 2048, m0, n0, ktiles, tid, lane, wave, acc);

#pragma unroll
  for (int i = 0; i < 2; ++i) {
    int gmB = m0 + wm + i * 16 + q * 4;
#pragma unroll
    for (int r = 0; r < 4; ++r) {
      float inv = 1.f / rs[gmB + r];
#pragma unroll
      for (int j = 0; j < 4; ++j) {
        int gn = n0 + wn + j * 16 + fm;
        C[(long)(gmB + r) * 1024 + gn] = acc[i][j][r] * inv;
      }
    }
  }
}

// ---------------------------------------------------------------------------
extern "C" void kernel_launch(void* const* d_in, const int* in_sizes, int n_in,
                              void* d_out, int out_size, void* d_ws, size_t ws_size,
                              hipStream_t stream) {
  const float* x = (const float*)d_in[0];
  const float* Wq = (const float*)d_in[1];
  const float* Wk = (const float*)d_in[2];
  const float* Wv = (const float*)d_in[3];
  float* out = (float*)d_out;

  // Layout: rowsums[32 KB] | Qr[16 MB] | Kr[16 MB] | Vt[16 MB] | xb[16 MB] |
  // Wb[6 MB]  (ws >= 70.06 MB guaranteed: R12-R14 always used Wb at +64 MB).
  // S0,S1 overlay xb (dead after v_gemm); S2,S3 live in d_out[0,1] region
  // (dead until pv writes out[2,3]).
  float* rowsums = (float*)d_ws;                      // [4][2048] fp32
  unsigned short* Qr = (unsigned short*)d_ws + 16384; // +32 KB
  unsigned short* Kr = Qr + (long)8192 * 1024;
  unsigned short* Vt = Kr + (long)8192 * 1024;        // [b][c][t]
  unsigned short* xb = Vt + (long)8192 * 1024;
  unsigned short* Wb = xb + (long)8192 * 1024;

  cvt_all<<<11265, 256, 0, stream>>>((const float4*)x, (const float4*)Wq,
                                     (const float4*)Wk, (const float4*)Wv,
                                     (ushort4*)xb, (ushort4*)Wb, (float4*)rowsums);

  qk_rope_gemm<<<dim3(64, 16), 256, 0, stream>>>(xb, Wb, Qr, Kr);
  v_gemm<<<dim3(64, 8), 256, 0, stream>>>(xb, Wb + (long)2048 * 1024, Vt);

  unsigned short* S01 = xb;                   // xb dead after v_gemm
  unsigned short* S23 = (unsigned short*)d_out;
  s_gemm<<<dim3(151, 1, 4), 256, 0, stream>>>(Qr, Kr, S01, S23, rowsums);
  // pv(z=2,3) first: reads S23 (out[0,1] region), writes out[2,3] (disjoint).
  pv_gemm<<<dim3(16, 32), 256, 0, stream>>>(S23, Vt, rowsums, out, 2);
  // pv(z=0,1): reads S01 (xb), writes out[0,1] (S23 already consumed).
  pv_gemm<<<dim3(16, 32), 256, 0, stream>>>(S01, Vt, rowsums, out, 0);
}

// Round 6
// 222.334 us; speedup vs baseline: 1.1050x; 1.1050x over previous
//
#include <hip/hip_runtime.h>

// ---------------------------------------------------------------------------
// RoPE attention: out = softmax(mask(RoPE(xWq^T) @ RoPE(xWk^T)^T / sqrt(d))) @ (xWv^T)
// B=4, T=2048, d=1024. fp32 in/out, bf16 MFMA internally.
// R17 -> R18: packed triangular S + restore known-good structure.
// Evidence: R14 dispatch stride 10 => 4 launches => BCH=4 ran, ws>=80MB;
// budget hole: cvt 11 + qk 42 + v 21 + s 43.5 = 117 of 245.7 => pv pair +
// gaps ~100-125us (pv ~200 TF-class, never yet in top-5). R16/17's pv split
// (2x512 blocks = 2/CU, zero queue) is the prime suspect (R12 failure mode).
// Changes:
//  (1) S stored PACKED: stripe bm = [128][min(bm+2,16)*128] ush at offset
//      bm(bm+3)/2*16384; 18.9 MB total fits xb(16)+Wb(6) free region =>
//      no d_out aliasing => pv is ONE 1024-block launch (3/CU + queue,
//      R14-proven balance). Every in-stripe position is written (0 when
//      masked) so pv reads no garbage; pv reads cols < (bm'+2)*64 <= len.
//  (2) qk+v merged back into qkv (removes a launch + 16MB xb re-read).
//  (3) 4 launches total: cvt, qkv, s, pv (stride-10 check next round).
// Same arithmetic & accumulation order => absmax must stay 0.01171875.
// Predicted: pv enters top-5 with real counters (FETCH>250MB => HBM-bound;
// else intensity-bound); total ~200-215 fast-container.
// ---------------------------------------------------------------------------

typedef float f32x4 __attribute__((ext_vector_type(4)));
typedef __bf16 bf16x8 __attribute__((ext_vector_type(8)));

#define BM 128
#define BN 128
#define BK 64  // ushorts per LDS tile row; 128x64x2B = 16 KB per buffer

// packed-S geometry: stripe bm (0..15) holds [128][len] with len=min(bm+2,16)*128
#define SP_BATCH 2473984  // 151 * 16384 ushorts per batch (4.72 MB)

__device__ __forceinline__ unsigned short f2bf(float f) {
  union { float f; unsigned int u; } c; c.f = f;
  unsigned int u = c.u;
  u += 0x7fffu + ((u >> 16) & 1u);  // round-nearest-even
  return (unsigned short)(u >> 16);
}
__device__ __forceinline__ float bf2f(unsigned short h) {
  union { unsigned int u; float f; } c; c.u = ((unsigned int)h) << 16;
  return c.f;
}

__device__ __forceinline__ void async16(const unsigned short* gp, unsigned short* lp) {
  __builtin_amdgcn_global_load_lds(
      (const __attribute__((address_space(1))) void*)gp,
      (__attribute__((address_space(3))) void*)lp, 16, 0, 0);
}

// ---------------------------------------------------------------------------
// All fp32->bf16 casts in one kernel; last block zeroes rowsums.
__global__ __launch_bounds__(256) void cvt_all(
    const float4* __restrict__ x, const float4* __restrict__ wq,
    const float4* __restrict__ wk, const float4* __restrict__ wv,
    ushort4* __restrict__ xb, ushort4* __restrict__ wb,
    float4* __restrict__ rowsums) {
  int b = blockIdx.x, t = threadIdx.x;
  if (b == 11264) {  // zero rowsums: 4*2048 fp32 = 2048 float4
#pragma unroll
    for (int i = 0; i < 8; ++i) rowsums[i * 256 + t] = float4{0.f, 0.f, 0.f, 0.f};
    return;
  }
  const float4* src;
  ushort4* dst;
  long i;
  if (b < 8192) { src = x; dst = xb; i = (long)b * 256 + t; }
  else if (b < 9216) { src = wq; dst = wb; i = (long)(b - 8192) * 256 + t; }
  else if (b < 10240) { src = wk; dst = wb + 262144; i = (long)(b - 9216) * 256 + t; }
  else { src = wv; dst = wb + 524288; i = (long)(b - 10240) * 256 + t; }
  float4 v = src[i];
  ushort4 o;
  o.x = f2bf(v.x); o.y = f2bf(v.y); o.z = f2bf(v.z); o.w = f2bf(v.w);
  dst[i] = o;
}

// ---------------------------------------------------------------------------
// NT-GEMM K-loop, BK=64, single-buffer global_load_lds staging.
// C[m,n] = sum_k A[m,k]*B[n,k]. A-tile = IM*32 rows, B-tile = JN*32 rows,
// 4 waves (2x2); each wave IM*16 x JN*16 via 16x16x32 frags, two k-steps of
// 32 per LDS tile. LDS position f=p*256+tid (16-B units) holds row
// f>>3 = p*32+srow; staged chunk c = (tid&7)^(srow&7) is p-invariant
// ((p*32)%8==0) -> base pointers + uniform per-iter adds. XOR swizzle keeps
// the DMA's lane-contiguous LDS layout conflict-free for frag reads.
template <int IM, int JN>
__device__ __forceinline__ void gemm_body(
    const unsigned short* __restrict__ A, const unsigned short* __restrict__ B,
    unsigned short* As, unsigned short* Bs,
    int lda, int ldb, int m0, int n0, int ktiles,
    int tid, int lane, int wave, f32x4 (&acc)[IM][JN]) {
  const int wm = (wave >> 1) * (IM * 16);
  const int wn = (wave & 1) * (JN * 16);
  const int fm = lane & 15;
  const int q = lane >> 4;
  const int srow = tid >> 3;                 // 0..31
  const int c = (tid & 7) ^ (srow & 7);      // staged 16-B chunk (p-invariant)
  const unsigned short* Ab = A + (long)(m0 + srow) * lda + c * 8;
  const unsigned short* Bb = B + (long)(n0 + srow) * ldb + c * 8;
  unsigned short* ldA = As + tid * 8;
  unsigned short* ldB = Bs + tid * 8;

  for (int kt = 0; kt < ktiles; ++kt) {
    const long k0 = (long)kt * BK;
    __syncthreads();  // prior frag reads done before LDS overwrite
#pragma unroll
    for (int p = 0; p < IM; ++p)
      async16(Ab + (long)(p * 32) * lda + k0, ldA + p * 2048);
#pragma unroll
    for (int p = 0; p < JN; ++p)
      async16(Bb + (long)(p * 32) * ldb + k0, ldB + p * 2048);
    __syncthreads();  // compiler drains vmcnt(0): tiles ready

#pragma unroll
    for (int s = 0; s < 2; ++s) {  // two k-steps of 32
      bf16x8 af[IM], bfr[JN];
#pragma unroll
      for (int i = 0; i < IM; ++i) {
        int row = wm + i * 16 + fm;
        af[i] = *(const bf16x8*)&As[row * 64 + ((((s << 2) | q) ^ (row & 7)) << 3)];
      }
#pragma unroll
      for (int j = 0; j < JN; ++j) {
        int row = wn + j * 16 + fm;
        bfr[j] = *(const bf16x8*)&Bs[row * 64 + ((((s << 2) | q) ^ (row & 7)) << 3)];
      }
#pragma unroll
      for (int i = 0; i < IM; ++i)
#pragma unroll
        for (int j = 0; j < JN; ++j)
          acc[i][j] = __builtin_amdgcn_mfma_f32_16x16x32_bf16(af[i], bfr[j], acc[i][j], 0, 0, 0);
    }
  }
}

// ---------------------------------------------------------------------------
// QKV projection + RoPE. A=xb[8192x1024], B=Wb[3072x1024]. Grid (bm=64, bn=24).
__global__ __launch_bounds__(256, 3) void qkv_rope_gemm(
    const unsigned short* __restrict__ A, const unsigned short* __restrict__ B,
    unsigned short* __restrict__ Qr, unsigned short* __restrict__ Kr,
    unsigned short* __restrict__ Vt) {
  __shared__ __align__(16) unsigned short As[BM * BK];
  __shared__ __align__(16) unsigned short Bs[BN * BK];
  const int tid = threadIdx.x, lane = tid & 63, wave = tid >> 6;
  const int bm = blockIdx.x, bn = blockIdx.y;
  const int m0 = bm * BM, n0 = bn * BN;
  const int wm = (wave >> 1) * 64, wn = (wave & 1) * 64;
  const int q = lane >> 4, fm = lane & 15;

  f32x4 acc[4][4];
#pragma unroll
  for (int i = 0; i < 4; ++i)
#pragma unroll
    for (int j = 0; j < 4; ++j) acc[i][j] = (f32x4)(0.f);

  gemm_body<4, 4>(A, B, As, Bs, 1024, 1024, m0, n0, 16, tid, lane, wave, acc);

  if (n0 < 2048) {
    // Q or K: RoPE (pair (2c,2c+1) in adjacent lanes), chained angle addition.
    const float NEG = -13.287712379549449f / 1024.f;  // -log2(1e4)/1024
    unsigned short* dst = (n0 < 1024) ? Qr : Kr;
    const int t00 = (m0 + wm + q * 4) & 2047;
#pragma unroll
    for (int j = 0; j < 4; ++j) {
      int c = (n0 & 1023) + wn + j * 16 + fm;
      float th = exp2f((float)(c & ~1) * NEG);
      float sgn = (c & 1) ? 1.f : -1.f;
      float ang0 = (float)t00 * th;
      float cb = __cosf(ang0), sb = __sinf(ang0);
      float c1 = __cosf(th), s1 = __sinf(th);
      float c16 = __cosf(16.f * th), s16 = __sinf(16.f * th);
#pragma unroll
      for (int i = 0; i < 4; ++i) {
        int gmB = m0 + wm + i * 16 + q * 4;
        float cr = cb, sr = sb;
#pragma unroll
        for (int r = 0; r < 4; ++r) {
          float v = acc[i][j][r];
          float p = __shfl_xor(v, 1);
          dst[(long)(gmB + r) * 1024 + c] = f2bf(v * cr + sgn * p * sr);
          float crn = cr * c1 - sr * s1;
          sr = sr * c1 + cr * s1;
          cr = crn;
        }
        float cbn = cb * c16 - sb * s16;
        sb = sb * c16 + cb * s16;
        cb = cbn;
      }
    }
  } else {
    // V: transpose to Vt[b][c][t]; 4 consecutive t per lane -> 8-B stores
    const int c0 = n0 - 2048;
#pragma unroll
    for (int j = 0; j < 4; ++j) {
      int c = c0 + wn + j * 16 + fm;
#pragma unroll
      for (int i = 0; i < 4; ++i) {
        int gmB = m0 + wm + i * 16 + q * 4;
        int b = gmB >> 11, t = gmB & 2047;
        ushort4 pk;
        pk.x = f2bf(acc[i][j][0]);
        pk.y = f2bf(acc[i][j][1]);
        pk.z = f2bf(acc[i][j][2]);
        pk.w = f2bf(acc[i][j][3]);
        *(ushort4*)&Vt[((long)b * 1024 + c) * 2048 + t] = pk;
      }
    }
  }
}

// ---------------------------------------------------------------------------
// E = exp(mask(Qr@Kr^T)/32) per batch (z), bf16 PACKED triangular, + rowsums.
// Compact triangular grid: 151 blocks/batch, decode (bm,bn) from linear idx.
// Stripe bm: [128][len], len = min(bm+2,16)*128, at Sp + z*SP_BATCH +
// bm(bm+3)/2*16384. Every in-stripe position written (0 when masked).
__global__ __launch_bounds__(256, 3) void s_gemm(
    const unsigned short* __restrict__ Qr, const unsigned short* __restrict__ Kr,
    unsigned short* __restrict__ Sp, float* __restrict__ rowsums) {
  __shared__ __align__(16) unsigned short As[BM * BK];
  __shared__ __align__(16) unsigned short Bs[BN * BK];
  const int tid = threadIdx.x, lane = tid & 63, wave = tid >> 6;
  const int z = blockIdx.z;
  int idx = blockIdx.x, bm = 0;
#pragma unroll 1
  for (; bm < 16; ++bm) {  // counts per bm: min(bm+2,16); total 151
    int cnt = (bm + 2 > 16) ? 16 : bm + 2;
    if (idx < cnt) break;
    idx -= cnt;
  }
  const int bn = idx;
  const unsigned short* A = Qr + (long)z * 2048 * 1024;
  const unsigned short* B = Kr + (long)z * 2048 * 1024;
  const int len = ((bm + 2 > 16) ? 16 : bm + 2) * 128;
  unsigned short* S = Sp + (long)z * SP_BATCH + (long)(bm * (bm + 3) / 2) * 16384;
  float* rs = rowsums + (long)z * 2048;
  const int m0 = bm * BM, n0 = bn * BN;
  const int wm = (wave >> 1) * 64, wn = (wave & 1) * 64;
  const int q = lane >> 4, fm = lane & 15;

  f32x4 acc[4][4];
#pragma unroll
  for (int i = 0; i < 4; ++i)
#pragma unroll
    for (int j = 0; j < 4; ++j) acc[i][j] = (f32x4)(0.f);

  gemm_body<4, 4>(A, B, As, Bs, 1024, 1024, m0, n0, 16, tid, lane, wave, acc);

  // rowsum scratch overlays Bs (frag reads complete after the final barrier)
  float* rsum = (float*)Bs;
  __syncthreads();
  if (tid < 128) rsum[tid] = 0.f;
  __syncthreads();

#pragma unroll
  for (int i = 0; i < 4; ++i) {
    int gmB = m0 + wm + i * 16 + q * 4;      // global row
    int lrow = wm + i * 16 + q * 4;          // stripe-local row
    float ps[4] = {0.f, 0.f, 0.f, 0.f};
#pragma unroll
    for (int j = 0; j < 4; ++j) {
      int gn = n0 + wn + j * 16 + fm;
#pragma unroll
      for (int r = 0; r < 4; ++r) {
        float e = (gn <= gmB + r + 1) ? __expf(acc[i][j][r] * 0.03125f) : 0.f;
        unsigned short h = f2bf(e);
        S[(long)(lrow + r) * len + gn] = h;
        ps[r] += bf2f(h);  // sum the rounded value (matches stored E)
      }
    }
#pragma unroll
    for (int r = 0; r < 4; ++r) {
      float v = ps[r];
      v += __shfl_xor(v, 1);
      v += __shfl_xor(v, 2);
      v += __shfl_xor(v, 4);
      v += __shfl_xor(v, 8);
      if (fm == 0) atomicAdd(&rsum[wm + i * 16 + q * 4 + r], v);
    }
  }
  __syncthreads();
  if (tid < 128) atomicAdd(&rs[m0 + tid], rsum[tid]);
}

// ---------------------------------------------------------------------------
// out = (E @ Vt^T) / rowsum, K-loop truncated causally. Tile 64x128 (IM=2).
// SINGLE launch, grid dim3(32, 32): bn = x&7, z = x>>3, bm = 31-y =>
// global long-first dispatch; 1024 blocks at 3/CU = 768 resident + 256
// queued for dynamic tail balance. A read from packed stripes:
// sb = bm>>1, lda = min(sb+2,16)*128, row offset (bm&1)*64.
__global__ __launch_bounds__(256, 3) void pv_gemm(
    const unsigned short* __restrict__ Sp, const unsigned short* __restrict__ Vt,
    const float* __restrict__ rowsums, float* __restrict__ out) {
  __shared__ __align__(16) unsigned short As[64 * BK];
  __shared__ __align__(16) unsigned short Bs[128 * BK];
  const int tid = threadIdx.x, lane = tid & 63, wave = tid >> 6;
  const int bn = blockIdx.x & 7;
  const int z = blockIdx.x >> 3;
  const int bm = 31 - blockIdx.y;  // 64-row granularity, longest-K first
  const int sb = bm >> 1;
  const int lda = ((sb + 2 > 16) ? 16 : sb + 2) * 128;
  const unsigned short* A = Sp + (long)z * SP_BATCH +
                            (long)(sb * (sb + 3) / 2) * 16384 +
                            (long)(bm & 1) * 64 * lda;
  const unsigned short* B = Vt + (long)z * 1024 * 2048;
  const float* rs = rowsums + (long)z * 2048;
  float* C = out + (long)z * 2048 * 1024;
  int ktiles = bm + 2;  // keys valid up to q+1, q <= m0+63; BK=64
  if (ktiles > 32) ktiles = 32;
  const int m0 = bm * 64, n0 = bn * 128;
  const int wm = (wave >> 1) * 32, wn = (wave & 1) * 64;
  const int q = lane >> 4, fm = lane & 15;

  f32x4 acc[2][4];
#pragma unroll
  for (int i = 0; i < 2; ++i)
#pragma unroll
    for (int j = 0; j < 4; ++j) acc[i][j] = (f32x4)(0.f);

  gemm_body<2, 4>(A, B, As, Bs, lda, 2048, 0, n0, ktiles, tid, lane, wave, acc);

#pragma unroll
  for (int i = 0; i < 2; ++i) {
    int gmB = m0 + wm + i * 16 + q * 4;
#pragma unroll
    for (int r = 0; r < 4; ++r) {
      float inv = 1.f / rs[gmB + r];
#pragma unroll
      for (int j = 0; j < 4; ++j) {
        int gn = n0 + wn + j * 16 + fm;
        C[(long)(gmB + r) * 1024 + gn] = acc[i][j][r] * inv;
      }
    }
  }
}

// ---------------------------------------------------------------------------
extern "C" void kernel_launch(void* const* d_in, const int* in_sizes, int n_in,
                              void* d_out, int out_size, void* d_ws, size_t ws_size,
                              hipStream_t stream) {
  const float* x = (const float*)d_in[0];
  const float* Wq = (const float*)d_in[1];
  const float* Wk = (const float*)d_in[2];
  const float* Wv = (const float*)d_in[3];
  float* out = (float*)d_out;

  // Layout: rowsums[32 KB] | Qr[16 MB] | Kr[16 MB] | Vt[16 MB] | xb[16 MB] |
  // Wb[6 MB]  (ws >= 70.06 MB established; R14 ran BCH=4 => ws >= 80 MB).
  // Packed S (18.9 MB) overlays xb+Wb, both dead after qkv_rope_gemm.
  float* rowsums = (float*)d_ws;                      // [4][2048] fp32
  unsigned short* Qr = (unsigned short*)d_ws + 16384; // +32 KB
  unsigned short* Kr = Qr + (long)8192 * 1024;
  unsigned short* Vt = Kr + (long)8192 * 1024;        // [b][c][t]
  unsigned short* xb = Vt + (long)8192 * 1024;
  unsigned short* Wb = xb + (long)8192 * 1024;

  cvt_all<<<11265, 256, 0, stream>>>((const float4*)x, (const float4*)Wq,
                                     (const float4*)Wk, (const float4*)Wv,
                                     (ushort4*)xb, (ushort4*)Wb, (float4*)rowsums);

  qkv_rope_gemm<<<dim3(64, 24), 256, 0, stream>>>(xb, Wb, Qr, Kr, Vt);

  unsigned short* Sp = xb;  // packed S: 4 x 4.72 MB, spans xb + 2.9 MB of Wb
  s_gemm<<<dim3(151, 1, 4), 256, 0, stream>>>(Qr, Kr, Sp, rowsums);
  pv_gemm<<<dim3(32, 32), 256, 0, stream>>>(Sp, Vt, rowsums, out);
}

// Round 7
// 219.211 us; speedup vs baseline: 1.1208x; 1.0142x over previous
//
#include <hip/hip_runtime.h>

// ---------------------------------------------------------------------------
// RoPE attention: out = softmax(mask(RoPE(xWq^T) @ RoPE(xWk^T)^T / sqrt(d))) @ (xWv^T)
// B=4, T=2048, d=1024. fp32 in/out, bf16 MFMA internally.
// R18 -> R19: occupancy/quantization attack. Budget (fast container): cvt 11
// + qkv 63.5 + s ~41 + pv ~35 (R17 bound: pv < 43.4 even split 2/CU) = 150;
// rest (~70us) is harness reset/gaps. s's deficit explained: 604 uniform
// blocks at 3/CU = all resident, 92 CUs x3 vs 164 x2 -> makespan 1.27x, plus
// epilogue. Changes:
//  (1) s_gemm 64x128 tiles (IM=2): 302/batch = 1208 blocks, uniform 16-kt
//      work, real queue; packed-S layout UNCHANGED (stripe sb=b>>1, row
//      offset (b&1)*64); fully-masked tiles (128bn > 64b+64, 15/batch)
//      skip GEMM, zero-fill only.
//  (2) __launch_bounds__(256,4) on qkv/s/pv (VGPR 56 <= 128 cap, LDS fits):
//      4 blocks/CU; pv 1024 = 4x256 exact.
// Predicted: s 43.5->~33 (Occ 18->~30), qkv -0-4, pv -3, total ~203-210.
// absmax ~0.0117 (rowsum atomic grouping changes; tolerance safe).
// If s unchanged -> balance theory dead -> R20 = 8-phase qkv port.
// ---------------------------------------------------------------------------

typedef float f32x4 __attribute__((ext_vector_type(4)));
typedef __bf16 bf16x8 __attribute__((ext_vector_type(8)));

#define BM 128
#define BN 128
#define BK 64  // ushorts per LDS tile row; 128x64x2B = 16 KB per buffer

// packed-S geometry: stripe sb (0..15) holds [128][len], len=min(sb+2,16)*128
#define SP_BATCH 2473984  // 151 * 16384 ushorts per batch (4.72 MB)

__device__ __forceinline__ unsigned short f2bf(float f) {
  union { float f; unsigned int u; } c; c.f = f;
  unsigned int u = c.u;
  u += 0x7fffu + ((u >> 16) & 1u);  // round-nearest-even
  return (unsigned short)(u >> 16);
}
__device__ __forceinline__ float bf2f(unsigned short h) {
  union { unsigned int u; float f; } c; c.u = ((unsigned int)h) << 16;
  return c.f;
}

__device__ __forceinline__ void async16(const unsigned short* gp, unsigned short* lp) {
  __builtin_amdgcn_global_load_lds(
      (const __attribute__((address_space(1))) void*)gp,
      (__attribute__((address_space(3))) void*)lp, 16, 0, 0);
}

// ---------------------------------------------------------------------------
// All fp32->bf16 casts in one kernel; last block zeroes rowsums.
__global__ __launch_bounds__(256) void cvt_all(
    const float4* __restrict__ x, const float4* __restrict__ wq,
    const float4* __restrict__ wk, const float4* __restrict__ wv,
    ushort4* __restrict__ xb, ushort4* __restrict__ wb,
    float4* __restrict__ rowsums) {
  int b = blockIdx.x, t = threadIdx.x;
  if (b == 11264) {  // zero rowsums: 4*2048 fp32 = 2048 float4
#pragma unroll
    for (int i = 0; i < 8; ++i) rowsums[i * 256 + t] = float4{0.f, 0.f, 0.f, 0.f};
    return;
  }
  const float4* src;
  ushort4* dst;
  long i;
  if (b < 8192) { src = x; dst = xb; i = (long)b * 256 + t; }
  else if (b < 9216) { src = wq; dst = wb; i = (long)(b - 8192) * 256 + t; }
  else if (b < 10240) { src = wk; dst = wb + 262144; i = (long)(b - 9216) * 256 + t; }
  else { src = wv; dst = wb + 524288; i = (long)(b - 10240) * 256 + t; }
  float4 v = src[i];
  ushort4 o;
  o.x = f2bf(v.x); o.y = f2bf(v.y); o.z = f2bf(v.z); o.w = f2bf(v.w);
  dst[i] = o;
}

// ---------------------------------------------------------------------------
// NT-GEMM K-loop, BK=64, single-buffer global_load_lds staging.
// C[m,n] = sum_k A[m,k]*B[n,k]. A-tile = IM*32 rows, B-tile = JN*32 rows,
// 4 waves (2x2); each wave IM*16 x JN*16 via 16x16x32 frags, two k-steps of
// 32 per LDS tile. LDS position f=p*256+tid (16-B units) holds row
// f>>3 = p*32+srow; staged chunk c = (tid&7)^(srow&7) is p-invariant
// ((p*32)%8==0) -> base pointers + uniform per-iter adds. XOR swizzle keeps
// the DMA's lane-contiguous LDS layout conflict-free for frag reads.
template <int IM, int JN>
__device__ __forceinline__ void gemm_body(
    const unsigned short* __restrict__ A, const unsigned short* __restrict__ B,
    unsigned short* As, unsigned short* Bs,
    int lda, int ldb, int m0, int n0, int ktiles,
    int tid, int lane, int wave, f32x4 (&acc)[IM][JN]) {
  const int wm = (wave >> 1) * (IM * 16);
  const int wn = (wave & 1) * (JN * 16);
  const int fm = lane & 15;
  const int q = lane >> 4;
  const int srow = tid >> 3;                 // 0..31
  const int c = (tid & 7) ^ (srow & 7);      // staged 16-B chunk (p-invariant)
  const unsigned short* Ab = A + (long)(m0 + srow) * lda + c * 8;
  const unsigned short* Bb = B + (long)(n0 + srow) * ldb + c * 8;
  unsigned short* ldA = As + tid * 8;
  unsigned short* ldB = Bs + tid * 8;

  for (int kt = 0; kt < ktiles; ++kt) {
    const long k0 = (long)kt * BK;
    __syncthreads();  // prior frag reads done before LDS overwrite
#pragma unroll
    for (int p = 0; p < IM; ++p)
      async16(Ab + (long)(p * 32) * lda + k0, ldA + p * 2048);
#pragma unroll
    for (int p = 0; p < JN; ++p)
      async16(Bb + (long)(p * 32) * ldb + k0, ldB + p * 2048);
    __syncthreads();  // compiler drains vmcnt(0): tiles ready

#pragma unroll
    for (int s = 0; s < 2; ++s) {  // two k-steps of 32
      bf16x8 af[IM], bfr[JN];
#pragma unroll
      for (int i = 0; i < IM; ++i) {
        int row = wm + i * 16 + fm;
        af[i] = *(const bf16x8*)&As[row * 64 + ((((s << 2) | q) ^ (row & 7)) << 3)];
      }
#pragma unroll
      for (int j = 0; j < JN; ++j) {
        int row = wn + j * 16 + fm;
        bfr[j] = *(const bf16x8*)&Bs[row * 64 + ((((s << 2) | q) ^ (row & 7)) << 3)];
      }
#pragma unroll
      for (int i = 0; i < IM; ++i)
#pragma unroll
        for (int j = 0; j < JN; ++j)
          acc[i][j] = __builtin_amdgcn_mfma_f32_16x16x32_bf16(af[i], bfr[j], acc[i][j], 0, 0, 0);
    }
  }
}

// ---------------------------------------------------------------------------
// QKV projection + RoPE. A=xb[8192x1024], B=Wb[3072x1024]. Grid (bm=64, bn=24).
__global__ __launch_bounds__(256, 4) void qkv_rope_gemm(
    const unsigned short* __restrict__ A, const unsigned short* __restrict__ B,
    unsigned short* __restrict__ Qr, unsigned short* __restrict__ Kr,
    unsigned short* __restrict__ Vt) {
  __shared__ __align__(16) unsigned short As[BM * BK];
  __shared__ __align__(16) unsigned short Bs[BN * BK];
  const int tid = threadIdx.x, lane = tid & 63, wave = tid >> 6;
  const int bm = blockIdx.x, bn = blockIdx.y;
  const int m0 = bm * BM, n0 = bn * BN;
  const int wm = (wave >> 1) * 64, wn = (wave & 1) * 64;
  const int q = lane >> 4, fm = lane & 15;

  f32x4 acc[4][4];
#pragma unroll
  for (int i = 0; i < 4; ++i)
#pragma unroll
    for (int j = 0; j < 4; ++j) acc[i][j] = (f32x4)(0.f);

  gemm_body<4, 4>(A, B, As, Bs, 1024, 1024, m0, n0, 16, tid, lane, wave, acc);

  if (n0 < 2048) {
    // Q or K: RoPE (pair (2c,2c+1) in adjacent lanes), chained angle addition.
    const float NEG = -13.287712379549449f / 1024.f;  // -log2(1e4)/1024
    unsigned short* dst = (n0 < 1024) ? Qr : Kr;
    const int t00 = (m0 + wm + q * 4) & 2047;
#pragma unroll
    for (int j = 0; j < 4; ++j) {
      int c = (n0 & 1023) + wn + j * 16 + fm;
      float th = exp2f((float)(c & ~1) * NEG);
      float sgn = (c & 1) ? 1.f : -1.f;
      float ang0 = (float)t00 * th;
      float cb = __cosf(ang0), sb = __sinf(ang0);
      float c1 = __cosf(th), s1 = __sinf(th);
      float c16 = __cosf(16.f * th), s16 = __sinf(16.f * th);
#pragma unroll
      for (int i = 0; i < 4; ++i) {
        int gmB = m0 + wm + i * 16 + q * 4;
        float cr = cb, sr = sb;
#pragma unroll
        for (int r = 0; r < 4; ++r) {
          float v = acc[i][j][r];
          float p = __shfl_xor(v, 1);
          dst[(long)(gmB + r) * 1024 + c] = f2bf(v * cr + sgn * p * sr);
          float crn = cr * c1 - sr * s1;
          sr = sr * c1 + cr * s1;
          cr = crn;
        }
        float cbn = cb * c16 - sb * s16;
        sb = sb * c16 + cb * s16;
        cb = cbn;
      }
    }
  } else {
    // V: transpose to Vt[b][c][t]; 4 consecutive t per lane -> 8-B stores
    const int c0 = n0 - 2048;
#pragma unroll
    for (int j = 0; j < 4; ++j) {
      int c = c0 + wn + j * 16 + fm;
#pragma unroll
      for (int i = 0; i < 4; ++i) {
        int gmB = m0 + wm + i * 16 + q * 4;
        int b = gmB >> 11, t = gmB & 2047;
        ushort4 pk;
        pk.x = f2bf(acc[i][j][0]);
        pk.y = f2bf(acc[i][j][1]);
        pk.z = f2bf(acc[i][j][2]);
        pk.w = f2bf(acc[i][j][3]);
        *(ushort4*)&Vt[((long)b * 1024 + c) * 2048 + t] = pk;
      }
    }
  }
}

// ---------------------------------------------------------------------------
// E = exp(mask(Qr@Kr^T)/32) per batch (z), bf16 PACKED triangular, + rowsums.
// 64x128 tiles (IM=2): grid 302/batch, decode b (64-row stripe, 31..0 long-
// first) and bn from compact idx; cnt(b) = min((b>>1)+2,16) so the FULL
// packed stripe width gets written (zeros where masked -> pv reads no
// garbage). Fully-masked tiles (128bn > 64b+64) skip the GEMM: zero-fill.
__global__ __launch_bounds__(256, 4) void s_gemm(
    const unsigned short* __restrict__ Qr, const unsigned short* __restrict__ Kr,
    unsigned short* __restrict__ Sp, float* __restrict__ rowsums) {
  __shared__ __align__(16) unsigned short As[64 * BK];
  __shared__ __align__(16) unsigned short Bs[BN * BK];
  const int tid = threadIdx.x, lane = tid & 63, wave = tid >> 6;
  const int z = blockIdx.z;
  int idx = blockIdx.x, b = 31;
#pragma unroll 1
  for (; b > 0; --b) {  // per-b counts: min((b>>1)+2,16); total 302
    int cnt = ((b >> 1) + 2 > 16) ? 16 : (b >> 1) + 2;
    if (idx < cnt) break;
    idx -= cnt;
  }
  const int bn = idx;
  const int sb = b >> 1;
  const int len = ((sb + 2 > 16) ? 16 : sb + 2) * 128;
  unsigned short* S = Sp + (long)z * SP_BATCH + (long)(sb * (sb + 3) / 2) * 16384 +
                      (long)(b & 1) * 64 * len;

  if (128 * bn > 64 * b + 64) {
    // fully masked: zero the 64x128 region, no rowsum contribution
    ushort4 zz{0, 0, 0, 0};
#pragma unroll
    for (int u = 0; u < 8; ++u) {
      int e = tid * 8 + u;            // 2048 ushort4 covers 64x128
      int row = e >> 5, c4 = e & 31;  // 32 ushort4 per row
      *(ushort4*)&S[(long)row * len + bn * 128 + c4 * 4] = zz;
    }
    return;
  }

  const unsigned short* A = Qr + (long)z * 2048 * 1024;
  const unsigned short* B = Kr + (long)z * 2048 * 1024;
  float* rs = rowsums + (long)z * 2048;
  const int m0 = b * 64, n0 = bn * 128;
  const int wm = (wave >> 1) * 32, wn = (wave & 1) * 64;
  const int q = lane >> 4, fm = lane & 15;

  f32x4 acc[2][4];
#pragma unroll
  for (int i = 0; i < 2; ++i)
#pragma unroll
    for (int j = 0; j < 4; ++j) acc[i][j] = (f32x4)(0.f);

  gemm_body<2, 4>(A, B, As, Bs, 1024, 1024, m0, n0, 16, tid, lane, wave, acc);

  // rowsum scratch overlays Bs (frag reads complete after the final barrier)
  float* rsum = (float*)Bs;
  __syncthreads();
  if (tid < 64) rsum[tid] = 0.f;
  __syncthreads();

#pragma unroll
  for (int i = 0; i < 2; ++i) {
    int lr = wm + i * 16 + q * 4;  // stripe-half-local row 0..63
    int gmB = m0 + lr;             // global row
    float ps[4] = {0.f, 0.f, 0.f, 0.f};
#pragma unroll
    for (int j = 0; j < 4; ++j) {
      int gn = n0 + wn + j * 16 + fm;
#pragma unroll
      for (int r = 0; r < 4; ++r) {
        float e = (gn <= gmB + r + 1) ? __expf(acc[i][j][r] * 0.03125f) : 0.f;
        unsigned short h = f2bf(e);
        S[(long)(lr + r) * len + gn] = h;
        ps[r] += bf2f(h);  // sum the rounded value (matches stored E)
      }
    }
#pragma unroll
    for (int r = 0; r < 4; ++r) {
      float v = ps[r];
      v += __shfl_xor(v, 1);
      v += __shfl_xor(v, 2);
      v += __shfl_xor(v, 4);
      v += __shfl_xor(v, 8);
      if (fm == 0) atomicAdd(&rsum[lr + r], v);
    }
  }
  __syncthreads();
  if (tid < 64) atomicAdd(&rs[m0 + tid], rsum[tid]);
}

// ---------------------------------------------------------------------------
// out = (E @ Vt^T) / rowsum, K-loop truncated causally. Tile 64x128 (IM=2).
// SINGLE launch, grid dim3(32, 32): bn = x&7, z = x>>3, bm = 31-y =>
// global long-first dispatch; 1024 blocks = 4/CU exact. A read from packed
// stripes: sb = bm>>1, lda = min(sb+2,16)*128, row offset (bm&1)*64.
__global__ __launch_bounds__(256, 4) void pv_gemm(
    const unsigned short* __restrict__ Sp, const unsigned short* __restrict__ Vt,
    const float* __restrict__ rowsums, float* __restrict__ out) {
  __shared__ __align__(16) unsigned short As[64 * BK];
  __shared__ __align__(16) unsigned short Bs[128 * BK];
  const int tid = threadIdx.x, lane = tid & 63, wave = tid >> 6;
  const int bn = blockIdx.x & 7;
  const int z = blockIdx.x >> 3;
  const int bm = 31 - blockIdx.y;  // 64-row granularity, longest-K first
  const int sb = bm >> 1;
  const int lda = ((sb + 2 > 16) ? 16 : sb + 2) * 128;
  const unsigned short* A = Sp + (long)z * SP_BATCH +
                            (long)(sb * (sb + 3) / 2) * 16384 +
                            (long)(bm & 1) * 64 * lda;
  const unsigned short* B = Vt + (long)z * 1024 * 2048;
  const float* rs = rowsums + (long)z * 2048;
  float* C = out + (long)z * 2048 * 1024;
  int ktiles = bm + 2;  // keys valid up to q+1, q <= m0+63; BK=64
  if (ktiles > 32) ktiles = 32;
  const int m0 = bm * 64, n0 = bn * 128;
  const int wm = (wave >> 1) * 32, wn = (wave & 1) * 64;
  const int q = lane >> 4, fm = lane & 15;

  f32x4 acc[2][4];
#pragma unroll
  for (int i = 0; i < 2; ++i)
#pragma unroll
    for (int j = 0; j < 4; ++j) acc[i][j] = (f32x4)(0.f);

  gemm_body<2, 4>(A, B, As, Bs, lda, 2048, 0, n0, ktiles, tid, lane, wave, acc);

#pragma unroll
  for (int i = 0; i < 2; ++i) {
    int gmB = m0 + wm + i * 16 + q * 4;
#pragma unroll
    for (int r = 0; r < 4; ++r) {
      float inv = 1.f / rs[gmB + r];
#pragma unroll
      for (int j = 0; j < 4; ++j) {
        int gn = n0 + wn + j * 16 + fm;
        C[(long)(gmB + r) * 1024 + gn] = acc[i][j][r] * inv;
      }
    }
  }
}

// ---------------------------------------------------------------------------
extern "C" void kernel_launch(void* const* d_in, const int* in_sizes, int n_in,
                              void* d_out, int out_size, void* d_ws, size_t ws_size,
                              hipStream_t stream) {
  const float* x = (const float*)d_in[0];
  const float* Wq = (const float*)d_in[1];
  const float* Wk = (const float*)d_in[2];
  const float* Wv = (const float*)d_in[3];
  float* out = (float*)d_out;

  // Layout: rowsums[32 KB] | Qr[16 MB] | Kr[16 MB] | Vt[16 MB] | xb[16 MB] |
  // Wb[6 MB]  (ws >= 80 MB established: R14 ran BCH=4).
  // Packed S (18.9 MB) overlays xb+Wb, both dead after qkv_rope_gemm.
  float* rowsums = (float*)d_ws;                      // [4][2048] fp32
  unsigned short* Qr = (unsigned short*)d_ws + 16384; // +32 KB
  unsigned short* Kr = Qr + (long)8192 * 1024;
  unsigned short* Vt = Kr + (long)8192 * 1024;        // [b][c][t]
  unsigned short* xb = Vt + (long)8192 * 1024;
  unsigned short* Wb = xb + (long)8192 * 1024;

  cvt_all<<<11265, 256, 0, stream>>>((const float4*)x, (const float4*)Wq,
                                     (const float4*)Wk, (const float4*)Wv,
                                     (ushort4*)xb, (ushort4*)Wb, (float4*)rowsums);

  qkv_rope_gemm<<<dim3(64, 24), 256, 0, stream>>>(xb, Wb, Qr, Kr, Vt);

  unsigned short* Sp = xb;  // packed S: 4 x 4.72 MB, spans xb + 2.9 MB of Wb
  s_gemm<<<dim3(302, 1, 4), 256, 0, stream>>>(Qr, Kr, Sp, rowsums);
  pv_gemm<<<dim3(32, 32), 256, 0, stream>>>(Sp, Vt, rowsums, out);
}